// Round 2
// baseline (76.624 us; speedup 1.0000x reference)
//
#include <hip/hip_runtime.h>
#include <math.h>

#define BB 64
#define PP 16
#define FIN 672
#define HH 2048
#define AA 32
#define MM (BB*PP)     // 1024
#define EPSBN 1e-5f

// ---------------------------------------------------------------------------
// Kernel 1: fused BN0 + GEMM1 (fp32, M=1024 x K=672 x N=2048) + BN1 + LIF.
// Produces S[row][n] = sum_t c_t * spike_t (weighted spike count).
// Tiling: 32x64 block tile (grid 32x32 = 1024 blocks -> 4 blocks/CU,
// 16 waves/CU), BK=16, 256 threads, 2x4 micro-tile, register prefetch of
// the next k-tile so global latency overlaps compute.
// ---------------------------------------------------------------------------
__global__ __launch_bounds__(256) void k_gemm1_lif(
    const float* __restrict__ x, const float* __restrict__ w1,
    const float* __restrict__ bias1,
    const float* __restrict__ g0, const float* __restrict__ b0,
    const float* __restrict__ m0, const float* __restrict__ v0,
    const float* __restrict__ g1, const float* __restrict__ b1,
    const float* __restrict__ m1, const float* __restrict__ v1,
    float* __restrict__ S)
{
    __shared__ float As[16][36];   // [k][m] 32 rows + pad4 (b64-aligned rows)
    __shared__ float Bs[16][68];   // [k][n] 64 cols + pad4

    const int tid = threadIdx.x;
    const int bx  = blockIdx.x;    // N tiles: 0..31
    const int by  = blockIdx.y;    // M tiles: 0..31

    // A (x) loading role: 32 rows x 16 k, one float2 per thread, BN0 fused.
    const int ar   = tid & 31;            // row in tile
    const int ak   = (tid >> 5) << 1;     // k offset 0,2,..,14
    const int grow = by * 32 + ar;
    const int pA   = grow & 15;
    const float a0  = g0[pA] / sqrtf(v0[pA] + EPSBN);
    const float be0 = b0[pA] - m0[pA] * a0;
    const float* xrow = x + (size_t)grow * FIN;

    // B (w1) loading role: 16 k x 64 cols, one float4 per thread.
    const int brk = tid >> 4;             // 0..15
    const int bcc = (tid & 15) << 2;      // 0..60
    const float* wp = w1 + (size_t)brk * HH + bx * 64 + bcc;

    const int tx = tid & 15;              // n-group (4 cols)
    const int ty = tid >> 4;              // m-group (2 rows), 0..15

    float acc[2][4];
    #pragma unroll
    for (int i = 0; i < 2; ++i)
        #pragma unroll
        for (int j = 0; j < 4; ++j) acc[i][j] = 0.f;

    // prefetch k-tile 0
    float2 aPre = *(const float2*)(xrow + ak);
    float4 bPre = *(const float4*)(wp);

    for (int kt = 0; kt < FIN; kt += 16) {
        As[ak + 0][ar] = fmaf(a0, aPre.x, be0);
        As[ak + 1][ar] = fmaf(a0, aPre.y, be0);
        *(float4*)&Bs[brk][bcc] = bPre;
        __syncthreads();
        if (kt + 16 < FIN) {
            aPre = *(const float2*)(xrow + kt + 16 + ak);
            bPre = *(const float4*)(wp + (size_t)(kt + 16) * HH);
        }
        #pragma unroll
        for (int k = 0; k < 16; ++k) {
            float2 a2 = *(const float2*)&As[k][ty << 1];
            float4 b4 = *(const float4*)&Bs[k][tx << 2];
            float aa[2] = {a2.x, a2.y};
            float bb[4] = {b4.x, b4.y, b4.z, b4.w};
            #pragma unroll
            for (int i = 0; i < 2; ++i)
                #pragma unroll
                for (int j = 0; j < 4; ++j)
                    acc[i][j] = fmaf(aa[i], bb[j], acc[i][j]);
        }
        __syncthreads();
    }

    // Weighted-spike coefficients c_t = (1 - 2^-(16-t))/16 (exact dyadic).
    const float KC[16] = {
        (1.0f-0x1p-16f)*0.0625f,(1.0f-0x1p-15f)*0.0625f,(1.0f-0x1p-14f)*0.0625f,(1.0f-0x1p-13f)*0.0625f,
        (1.0f-0x1p-12f)*0.0625f,(1.0f-0x1p-11f)*0.0625f,(1.0f-0x1p-10f)*0.0625f,(1.0f-0x1p-9f)*0.0625f,
        (1.0f-0x1p-8f)*0.0625f,(1.0f-0x1p-7f)*0.0625f,(1.0f-0x1p-6f)*0.0625f,(1.0f-0x1p-5f)*0.0625f,
        (1.0f-0x1p-4f)*0.0625f,(1.0f-0x1p-3f)*0.0625f,(1.0f-0x1p-2f)*0.0625f,(1.0f-0x1p-1f)*0.0625f
    };

    const int col0 = bx * 64 + (tx << 2);
    float4 bias4 = *(const float4*)(bias1 + col0);
    const float bias_arr[4] = {bias4.x, bias4.y, bias4.z, bias4.w};

    #pragma unroll
    for (int i = 0; i < 2; ++i) {
        const int r = by * 32 + (ty << 1) + i;
        const int p = r & 15;
        const float a1  = g1[p] / sqrtf(v1[p] + EPSBN);
        const float be1 = b1[p] - m1[p] * a1;
        float out4[4];
        #pragma unroll
        for (int j = 0; j < 4; ++j) {
            const float h = fmaf(a1, acc[i][j] + bias_arr[j], be1);
            float v = 0.f, s = 0.f;
            #pragma unroll
            for (int t = 0; t < 16; ++t) {
                v = v + (h - v) * 0.5f;
                if (v >= 1.0f) { s += KC[t]; v = 0.f; }
            }
            out4[j] = s;
        }
        float4 sv; sv.x = out4[0]; sv.y = out4[1]; sv.z = out4[2]; sv.w = out4[3];
        *(float4*)(S + (size_t)r * HH + col0) = sv;
    }
}

// ---------------------------------------------------------------------------
// Kernel 2a: partial GEMM2: part[kc][row][col] = sum_{k in chunk} S[row,k]*w2[k,col]
// Grid: (128 row-groups of 8) x (8 K-chunks of 256). w2 chunk staged in LDS.
// ---------------------------------------------------------------------------
__global__ __launch_bounds__(256) void k_gemm2_part(
    const float* __restrict__ S, const float* __restrict__ w2,
    float* __restrict__ part)
{
    __shared__ float w2s[8192];   // 256 k x 32 cols = 32 KB
    const int tid = threadIdx.x;
    const int rg  = blockIdx.x;   // 0..127
    const int kc  = blockIdx.y;   // 0..7

    const float4* src = (const float4*)(w2 + (size_t)kc * 8192);
    #pragma unroll
    for (int i = tid; i < 2048; i += 256) ((float4*)w2s)[i] = src[i];
    __syncthreads();

    const int rw  = tid >> 5;     // 0..7
    const int col = tid & 31;
    const int row = rg * 8 + rw;
    const float* Sp = S + (size_t)row * HH + kc * 256;

    float acc0 = 0.f, acc1 = 0.f;
    #pragma unroll 4
    for (int j = 0; j < 256; j += 4) {
        float4 s4 = *(const float4*)(Sp + j);
        acc0 = fmaf(s4.x, w2s[(j + 0) * 32 + col], acc0);
        acc1 = fmaf(s4.y, w2s[(j + 1) * 32 + col], acc1);
        acc0 = fmaf(s4.z, w2s[(j + 2) * 32 + col], acc0);
        acc1 = fmaf(s4.w, w2s[(j + 3) * 32 + col], acc1);
    }
    part[((size_t)kc * MM + row) * AA + col] = acc0 + acc1;
}

// ---------------------------------------------------------------------------
// Kernel 2b: reduce 8 partials + folded BN2 / bias2 / ns-LIF-mean + tanh*2.
// ---------------------------------------------------------------------------
__global__ __launch_bounds__(256) void k_finish(
    const float* __restrict__ part, const float* __restrict__ bias2,
    const float* __restrict__ g2, const float* __restrict__ b2,
    const float* __restrict__ m2, const float* __restrict__ v2,
    float* __restrict__ out)
{
    const int i   = blockIdx.x * 256 + threadIdx.x;  // 0..32767
    const int col = i & 31;
    const int row = i >> 5;
    const int p   = row & 15;
    float acc = 0.f;
    #pragma unroll
    for (int s = 0; s < 8; ++s) acc += part[(size_t)s * MM * AA + i];
    const float a2   = g2[p] / sqrtf(v2[p] + EPSBN);
    const float be2  = b2[p] - m2[p] * a2;
    const float Csum = 0.9375f + 0x1p-20f;  // sum_t c_t
    const float val  = fmaf(a2, acc + Csum * bias2[col], Csum * be2);
    out[i] = 2.0f * tanhf(val);
}

extern "C" void kernel_launch(void* const* d_in, const int* in_sizes, int n_in,
                              void* d_out, int out_size, void* d_ws, size_t ws_size,
                              hipStream_t stream) {
    (void)in_sizes; (void)n_in; (void)out_size; (void)ws_size;
    const float* x     = (const float*)d_in[0];
    const float* w1    = (const float*)d_in[1];
    const float* bias1 = (const float*)d_in[2];
    const float* w2    = (const float*)d_in[3];
    const float* bias2 = (const float*)d_in[4];
    const float* g0 = (const float*)d_in[5];
    const float* b0 = (const float*)d_in[6];
    const float* m0 = (const float*)d_in[7];
    const float* v0 = (const float*)d_in[8];
    const float* g1 = (const float*)d_in[9];
    const float* b1 = (const float*)d_in[10];
    const float* m1 = (const float*)d_in[11];
    const float* v1 = (const float*)d_in[12];
    const float* g2 = (const float*)d_in[13];
    const float* b2 = (const float*)d_in[14];
    const float* m2 = (const float*)d_in[15];
    const float* v2 = (const float*)d_in[16];

    float* S    = (float*)d_ws;                                            // 8 MB
    float* part = (float*)((char*)d_ws + (size_t)MM * HH * sizeof(float)); // +1 MB
    float* out  = (float*)d_out;

    k_gemm1_lif<<<dim3(32, 32), 256, 0, stream>>>(x, w1, bias1,
                                                  g0, b0, m0, v0,
                                                  g1, b1, m1, v1, S);
    k_gemm2_part<<<dim3(128, 8), 256, 0, stream>>>(S, w2, part);
    k_finish<<<dim3(128), 256, 0, stream>>>(part, bias2, g2, b2, m2, v2, out);
}

// Round 3
// 50.018 us; speedup vs baseline: 1.5319x; 1.5319x over previous
//
#include <hip/hip_runtime.h>
#include <math.h>

#define BB 64
#define PP 16
#define FIN 672
#define HH 2048
#define AA 32
#define MM (BB*PP)     // 1024
#define EPSBN 1e-5f
#define NKB 21         // FIN/32

typedef _Float16 f16;
typedef __attribute__((ext_vector_type(8))) _Float16 half8;
typedef __attribute__((ext_vector_type(4))) float floatx4;

// ---------------------------------------------------------------------------
// Prep A: BN0(x) -> fp16 hi/lo planes in MFMA-A fragment order.
// Fragment (mb,kb): lane l holds A[mb*16 + (l&15)][kb*32 + (l>>4)*8 + 0..7].
// Stored contiguously: plane[((mb*21)+kb)*64 + lane][8].
// ---------------------------------------------------------------------------
__global__ __launch_bounds__(256) void k_prep_a(
    const float* __restrict__ x,
    const float* __restrict__ g0, const float* __restrict__ b0,
    const float* __restrict__ m0, const float* __restrict__ v0,
    f16* __restrict__ Ah, f16* __restrict__ Al)
{
    const int idx  = blockIdx.x * 256 + threadIdx.x;   // 64*21*64 = 86016
    const int lane = idx & 63;
    const int t    = idx >> 6;
    const int kb   = t % NKB;
    const int mb   = t / NKB;
    const int row  = mb * 16 + (lane & 15);
    const int k0   = kb * 32 + ((lane >> 4) << 3);
    const int p    = row & 15;
    const float a0  = g0[p] / sqrtf(v0[p] + EPSBN);
    const float be0 = b0[p] - m0[p] * a0;
    const float* xp = x + (size_t)row * FIN + k0;
    float4 u0 = *(const float4*)xp;
    float4 u1 = *(const float4*)(xp + 4);
    const float xs[8] = {u0.x,u0.y,u0.z,u0.w,u1.x,u1.y,u1.z,u1.w};
    half8 hi, lo;
    #pragma unroll
    for (int j = 0; j < 8; ++j) {
        const float xn = fmaf(a0, xs[j], be0);
        const f16 h = (f16)xn;
        hi[j] = h;
        lo[j] = (f16)(xn - (float)h);
    }
    *(half8*)(Ah + (size_t)idx * 8) = hi;
    *(half8*)(Al + (size_t)idx * 8) = lo;
}

// ---------------------------------------------------------------------------
// Prep W: w1 -> fp16 hi/lo planes in MFMA-B fragment order.
// Fragment (nb,kb): lane l holds W[kb*32 + (l>>4)*8 + 0..7][nb*16 + (l&15)].
// ---------------------------------------------------------------------------
__global__ __launch_bounds__(256) void k_prep_w(
    const float* __restrict__ w1, f16* __restrict__ Wh, f16* __restrict__ Wl)
{
    const int idx  = blockIdx.x * 256 + threadIdx.x;   // 128*21*64 = 172032
    const int lane = idx & 63;
    const int t    = idx >> 6;
    const int kb   = t % NKB;
    const int nb   = t / NKB;
    const int col  = nb * 16 + (lane & 15);
    const int k0   = kb * 32 + ((lane >> 4) << 3);
    half8 hi, lo;
    #pragma unroll
    for (int j = 0; j < 8; ++j) {
        const float wv = w1[(size_t)(k0 + j) * HH + col];
        const f16 h = (f16)wv;
        hi[j] = h;
        lo[j] = (f16)(wv - (float)h);
    }
    *(half8*)(Wh + (size_t)idx * 8) = hi;
    *(half8*)(Wl + (size_t)idx * 8) = lo;
}

// ---------------------------------------------------------------------------
// GEMM1 via MFMA fp16-split (hh + hl + lh), fused bias1/BN1/LIF epilogue.
// Block = 64(M) x 128(N), 4 waves (2x2), wave tile 32x64 = 2x4 16x16 frags.
// No LDS, no barriers: frag-ordered operands stream from L2.
// ---------------------------------------------------------------------------
__global__ __launch_bounds__(256) void k_gemm1_mfma(
    const f16* __restrict__ Ah, const f16* __restrict__ Al,
    const f16* __restrict__ Wh, const f16* __restrict__ Wl,
    const float* __restrict__ bias1,
    const float* __restrict__ g1, const float* __restrict__ b1,
    const float* __restrict__ m1, const float* __restrict__ v1,
    float* __restrict__ S)
{
    const int tid  = threadIdx.x;
    const int lane = tid & 63;
    const int w    = tid >> 6;
    const int wm   = w >> 1, wn = w & 1;
    const int bx   = blockIdx.x;   // 16 col tiles of 128
    const int by   = blockIdx.y;   // 16 row tiles of 64

    size_t baseA[2], baseB[4];
    #pragma unroll
    for (int m = 0; m < 2; ++m)
        baseA[m] = ((size_t)(by * 4 + wm * 2 + m) * NKB) * 64 + lane;
    #pragma unroll
    for (int n = 0; n < 4; ++n)
        baseB[n] = ((size_t)(bx * 8 + wn * 4 + n) * NKB) * 64 + lane;

    const half8* pAh = (const half8*)Ah;
    const half8* pAl = (const half8*)Al;
    const half8* pWh = (const half8*)Wh;
    const half8* pWl = (const half8*)Wl;

    floatx4 acc[2][4];
    #pragma unroll
    for (int m = 0; m < 2; ++m)
        #pragma unroll
        for (int n = 0; n < 4; ++n) acc[m][n] = (floatx4){0.f,0.f,0.f,0.f};

    half8 a0h[2], a0l[2], b0h[4], b0l[4];
    half8 a1h[2], a1l[2], b1h[4], b1l[4];

#define LOADK(kb, ah, al, bh, bl) do {                                        \
    _Pragma("unroll") for (int m_ = 0; m_ < 2; ++m_) {                        \
        ah[m_] = pAh[baseA[m_] + (size_t)(kb) * 64];                          \
        al[m_] = pAl[baseA[m_] + (size_t)(kb) * 64]; }                        \
    _Pragma("unroll") for (int n_ = 0; n_ < 4; ++n_) {                        \
        bh[n_] = pWh[baseB[n_] + (size_t)(kb) * 64];                          \
        bl[n_] = pWl[baseB[n_] + (size_t)(kb) * 64]; }                        \
} while (0)

#define COMPUTE(ah, al, bh, bl) do {                                          \
    _Pragma("unroll") for (int m_ = 0; m_ < 2; ++m_)                          \
    _Pragma("unroll") for (int n_ = 0; n_ < 4; ++n_)                          \
        acc[m_][n_] = __builtin_amdgcn_mfma_f32_16x16x32_f16(                 \
            ah[m_], bh[n_], acc[m_][n_], 0, 0, 0);                            \
    _Pragma("unroll") for (int m_ = 0; m_ < 2; ++m_)                          \
    _Pragma("unroll") for (int n_ = 0; n_ < 4; ++n_)                          \
        acc[m_][n_] = __builtin_amdgcn_mfma_f32_16x16x32_f16(                 \
            ah[m_], bl[n_], acc[m_][n_], 0, 0, 0);                            \
    _Pragma("unroll") for (int m_ = 0; m_ < 2; ++m_)                          \
    _Pragma("unroll") for (int n_ = 0; n_ < 4; ++n_)                          \
        acc[m_][n_] = __builtin_amdgcn_mfma_f32_16x16x32_f16(                 \
            al[m_], bh[n_], acc[m_][n_], 0, 0, 0);                            \
} while (0)

    LOADK(0, a0h, a0l, b0h, b0l);
    for (int kb = 0; kb + 2 <= NKB; kb += 2) {
        LOADK(kb + 1, a1h, a1l, b1h, b1l);
        COMPUTE(a0h, a0l, b0h, b0l);
        if (kb + 2 < NKB) LOADK(kb + 2, a0h, a0l, b0h, b0l);
        COMPUTE(a1h, a1l, b1h, b1l);
    }
    COMPUTE(a0h, a0l, b0h, b0l);   // kb = 20 (NKB odd)
#undef LOADK
#undef COMPUTE

    // Weighted-spike coefficients c_t = (1 - 2^-(16-t))/16 (exact dyadic).
    const float KC[16] = {
        (1.0f-0x1p-16f)*0.0625f,(1.0f-0x1p-15f)*0.0625f,(1.0f-0x1p-14f)*0.0625f,(1.0f-0x1p-13f)*0.0625f,
        (1.0f-0x1p-12f)*0.0625f,(1.0f-0x1p-11f)*0.0625f,(1.0f-0x1p-10f)*0.0625f,(1.0f-0x1p-9f)*0.0625f,
        (1.0f-0x1p-8f)*0.0625f,(1.0f-0x1p-7f)*0.0625f,(1.0f-0x1p-6f)*0.0625f,(1.0f-0x1p-5f)*0.0625f,
        (1.0f-0x1p-4f)*0.0625f,(1.0f-0x1p-3f)*0.0625f,(1.0f-0x1p-2f)*0.0625f,(1.0f-0x1p-1f)*0.0625f
    };

    const int r4 = (lane >> 4) << 2;
    #pragma unroll
    for (int m = 0; m < 2; ++m) {
        const int rowbase = by * 64 + wm * 32 + m * 16 + r4;
        #pragma unroll
        for (int j = 0; j < 4; ++j) {
            const int row = rowbase + j;
            const int p   = row & 15;
            const float a1  = g1[p] / sqrtf(v1[p] + EPSBN);
            const float be1 = b1[p] - m1[p] * a1;
            #pragma unroll
            for (int n = 0; n < 4; ++n) {
                const int col = bx * 128 + wn * 64 + n * 16 + (lane & 15);
                const float h = fmaf(a1, acc[m][n][j] + bias1[col], be1);
                float v = 0.f, s = 0.f;
                #pragma unroll
                for (int t = 0; t < 16; ++t) {
                    v = v + (h - v) * 0.5f;
                    if (v >= 1.0f) { s += KC[t]; v = 0.f; }
                }
                S[(size_t)row * HH + col] = s;
            }
        }
    }
}

// ---------------------------------------------------------------------------
// Fallback fp32 GEMM1 (round-2 kernel) used if ws_size is too small.
// ---------------------------------------------------------------------------
__global__ __launch_bounds__(256) void k_gemm1_fp32(
    const float* __restrict__ x, const float* __restrict__ w1,
    const float* __restrict__ bias1,
    const float* __restrict__ g0, const float* __restrict__ b0,
    const float* __restrict__ m0, const float* __restrict__ v0,
    const float* __restrict__ g1, const float* __restrict__ b1,
    const float* __restrict__ m1, const float* __restrict__ v1,
    float* __restrict__ S)
{
    __shared__ float As[16][36];
    __shared__ float Bs[16][68];

    const int tid = threadIdx.x;
    const int bx  = blockIdx.x;
    const int by  = blockIdx.y;

    const int ar   = tid & 31;
    const int ak   = (tid >> 5) << 1;
    const int grow = by * 32 + ar;
    const int pA   = grow & 15;
    const float a0  = g0[pA] / sqrtf(v0[pA] + EPSBN);
    const float be0 = b0[pA] - m0[pA] * a0;
    const float* xrow = x + (size_t)grow * FIN;

    const int brk = tid >> 4;
    const int bcc = (tid & 15) << 2;
    const float* wp = w1 + (size_t)brk * HH + bx * 64 + bcc;

    const int tx = tid & 15;
    const int ty = tid >> 4;

    float acc[2][4];
    #pragma unroll
    for (int i = 0; i < 2; ++i)
        #pragma unroll
        for (int j = 0; j < 4; ++j) acc[i][j] = 0.f;

    float2 aPre = *(const float2*)(xrow + ak);
    float4 bPre = *(const float4*)(wp);

    for (int kt = 0; kt < FIN; kt += 16) {
        As[ak + 0][ar] = fmaf(a0, aPre.x, be0);
        As[ak + 1][ar] = fmaf(a0, aPre.y, be0);
        *(float4*)&Bs[brk][bcc] = bPre;
        __syncthreads();
        if (kt + 16 < FIN) {
            aPre = *(const float2*)(xrow + kt + 16 + ak);
            bPre = *(const float4*)(wp + (size_t)(kt + 16) * HH);
        }
        #pragma unroll
        for (int k = 0; k < 16; ++k) {
            float2 a2 = *(const float2*)&As[k][ty << 1];
            float4 b4 = *(const float4*)&Bs[k][tx << 2];
            float aa[2] = {a2.x, a2.y};
            float bb[4] = {b4.x, b4.y, b4.z, b4.w};
            #pragma unroll
            for (int i = 0; i < 2; ++i)
                #pragma unroll
                for (int j = 0; j < 4; ++j)
                    acc[i][j] = fmaf(aa[i], bb[j], acc[i][j]);
        }
        __syncthreads();
    }

    const float KC[16] = {
        (1.0f-0x1p-16f)*0.0625f,(1.0f-0x1p-15f)*0.0625f,(1.0f-0x1p-14f)*0.0625f,(1.0f-0x1p-13f)*0.0625f,
        (1.0f-0x1p-12f)*0.0625f,(1.0f-0x1p-11f)*0.0625f,(1.0f-0x1p-10f)*0.0625f,(1.0f-0x1p-9f)*0.0625f,
        (1.0f-0x1p-8f)*0.0625f,(1.0f-0x1p-7f)*0.0625f,(1.0f-0x1p-6f)*0.0625f,(1.0f-0x1p-5f)*0.0625f,
        (1.0f-0x1p-4f)*0.0625f,(1.0f-0x1p-3f)*0.0625f,(1.0f-0x1p-2f)*0.0625f,(1.0f-0x1p-1f)*0.0625f
    };

    const int col0 = bx * 64 + (tx << 2);
    float4 bias4 = *(const float4*)(bias1 + col0);
    const float bias_arr[4] = {bias4.x, bias4.y, bias4.z, bias4.w};

    #pragma unroll
    for (int i = 0; i < 2; ++i) {
        const int r = by * 32 + (ty << 1) + i;
        const int p = r & 15;
        const float a1  = g1[p] / sqrtf(v1[p] + EPSBN);
        const float be1 = b1[p] - m1[p] * a1;
        float out4[4];
        #pragma unroll
        for (int j = 0; j < 4; ++j) {
            const float h = fmaf(a1, acc[i][j] + bias_arr[j], be1);
            float v = 0.f, s = 0.f;
            #pragma unroll
            for (int t = 0; t < 16; ++t) {
                v = v + (h - v) * 0.5f;
                if (v >= 1.0f) { s += KC[t]; v = 0.f; }
            }
            out4[j] = s;
        }
        float4 sv; sv.x = out4[0]; sv.y = out4[1]; sv.z = out4[2]; sv.w = out4[3];
        *(float4*)(S + (size_t)r * HH + col0) = sv;
    }
}

// ---------------------------------------------------------------------------
// Kernel 2a: partial GEMM2; Kernel 2b: reduce + BN2/bias2/ns-LIF-mean + tanh.
// ---------------------------------------------------------------------------
__global__ __launch_bounds__(256) void k_gemm2_part(
    const float* __restrict__ S, const float* __restrict__ w2,
    float* __restrict__ part)
{
    __shared__ float w2s[8192];
    const int tid = threadIdx.x;
    const int rg  = blockIdx.x;
    const int kc  = blockIdx.y;

    const float4* src = (const float4*)(w2 + (size_t)kc * 8192);
    #pragma unroll
    for (int i = tid; i < 2048; i += 256) ((float4*)w2s)[i] = src[i];
    __syncthreads();

    const int rw  = tid >> 5;
    const int col = tid & 31;
    const int row = rg * 8 + rw;
    const float* Sp = S + (size_t)row * HH + kc * 256;

    float acc0 = 0.f, acc1 = 0.f;
    #pragma unroll 4
    for (int j = 0; j < 256; j += 4) {
        float4 s4 = *(const float4*)(Sp + j);
        acc0 = fmaf(s4.x, w2s[(j + 0) * 32 + col], acc0);
        acc1 = fmaf(s4.y, w2s[(j + 1) * 32 + col], acc1);
        acc0 = fmaf(s4.z, w2s[(j + 2) * 32 + col], acc0);
        acc1 = fmaf(s4.w, w2s[(j + 3) * 32 + col], acc1);
    }
    part[((size_t)kc * MM + row) * AA + col] = acc0 + acc1;
}

__global__ __launch_bounds__(256) void k_finish(
    const float* __restrict__ part, const float* __restrict__ bias2,
    const float* __restrict__ g2, const float* __restrict__ b2,
    const float* __restrict__ m2, const float* __restrict__ v2,
    float* __restrict__ out)
{
    const int i   = blockIdx.x * 256 + threadIdx.x;
    const int col = i & 31;
    const int row = i >> 5;
    const int p   = row & 15;
    float acc = 0.f;
    #pragma unroll
    for (int s = 0; s < 8; ++s) acc += part[(size_t)s * MM * AA + i];
    const float a2   = g2[p] / sqrtf(v2[p] + EPSBN);
    const float be2  = b2[p] - m2[p] * a2;
    const float Csum = 0.9375f + 0x1p-20f;
    const float val  = fmaf(a2, acc + Csum * bias2[col], Csum * be2);
    out[i] = 2.0f * tanhf(val);
}

extern "C" void kernel_launch(void* const* d_in, const int* in_sizes, int n_in,
                              void* d_out, int out_size, void* d_ws, size_t ws_size,
                              hipStream_t stream) {
    (void)in_sizes; (void)n_in; (void)out_size;
    const float* x     = (const float*)d_in[0];
    const float* w1    = (const float*)d_in[1];
    const float* bias1 = (const float*)d_in[2];
    const float* w2    = (const float*)d_in[3];
    const float* bias2 = (const float*)d_in[4];
    const float* g0 = (const float*)d_in[5];
    const float* b0 = (const float*)d_in[6];
    const float* m0 = (const float*)d_in[7];
    const float* v0 = (const float*)d_in[8];
    const float* g1 = (const float*)d_in[9];
    const float* b1 = (const float*)d_in[10];
    const float* m1 = (const float*)d_in[11];
    const float* v1 = (const float*)d_in[12];
    const float* g2 = (const float*)d_in[13];
    const float* b2 = (const float*)d_in[14];
    const float* m2 = (const float*)d_in[15];
    const float* v2 = (const float*)d_in[16];
    float* out = (float*)d_out;

    // ws layout (MFMA path): Ah 1.3M | Al 1.3M | Wh 2.6M | Wl 2.6M | S 8M | part 1M
    const size_t offAl   = 1376256;
    const size_t offWh   = 2752512;
    const size_t offWl   = 5505024;
    const size_t offS    = 8257536;
    const size_t offPart = offS + 8388608;
    const size_t needed  = offPart + 1048576;   // 17694720

    if (ws_size >= needed) {
        f16* Ah = (f16*)d_ws;
        f16* Al = (f16*)((char*)d_ws + offAl);
        f16* Wh = (f16*)((char*)d_ws + offWh);
        f16* Wl = (f16*)((char*)d_ws + offWl);
        float* S    = (float*)((char*)d_ws + offS);
        float* part = (float*)((char*)d_ws + offPart);

        k_prep_a<<<336, 256, 0, stream>>>(x, g0, b0, m0, v0, Ah, Al);
        k_prep_w<<<672, 256, 0, stream>>>(w1, Wh, Wl);
        k_gemm1_mfma<<<dim3(16, 16), 256, 0, stream>>>(Ah, Al, Wh, Wl, bias1,
                                                       g1, b1, m1, v1, S);
        k_gemm2_part<<<dim3(128, 8), 256, 0, stream>>>(S, w2, part);
        k_finish<<<dim3(128), 256, 0, stream>>>(part, bias2, g2, b2, m2, v2, out);
    } else {
        float* S    = (float*)d_ws;
        float* part = (float*)((char*)d_ws + (size_t)MM * HH * sizeof(float));
        k_gemm1_fp32<<<dim3(32, 32), 256, 0, stream>>>(x, w1, bias1,
                                                       g0, b0, m0, v0,
                                                       g1, b1, m1, v1, S);
        k_gemm2_part<<<dim3(128, 8), 256, 0, stream>>>(S, w2, part);
        k_finish<<<dim3(128), 256, 0, stream>>>(part, bias2, g2, b2, m2, v2, out);
    }
}

// Round 4
// 43.865 us; speedup vs baseline: 1.7468x; 1.1403x over previous
//
#include <hip/hip_runtime.h>
#include <math.h>

#define BB 64
#define PP 16
#define FIN 672
#define HH 2048
#define AA 32
#define MM (BB*PP)     // 1024
#define EPSBN 1e-5f
#define NKB 21         // FIN/32

typedef _Float16 f16;
typedef __attribute__((ext_vector_type(8))) _Float16 half8;
typedef __attribute__((ext_vector_type(4))) float floatx4;

// S(h) for the 16-step LIF with constant drive h: spike period m = ceil(log2(h/(h-1))),
// S = sum over spikes q*m<=16 of KC[q*m-1]; exact dyadic values precomputed.
__device__ const float LIF_LUT[18] = {
    0.0f,
    0.93750095367431640625f,   // m=1  (0.9375 + 2^-20)
    0.4583339691162109375f,    // m=2
    0.294643402099609375f,     // m=3
    0.21666717529296875f,      // m=4
    0.1713714599609375f,       // m=5
    0.123016357421875f,        // m=6
    0.11712646484375f,         // m=7
    0.0936279296875f,          // m=8
    0.062255859375f,           // m=9
    0.06201171875f,            // m=10
    0.0615234375f,             // m=11
    0.060546875f,              // m=12
    0.05859375f,               // m=13
    0.0546875f,                // m=14
    0.046875f,                 // m=15
    0.03125f,                  // m=16
    0.0f                       // m>=17: no spike
};

// ---------------------------------------------------------------------------
// Prep A: x -> (BN0) -> fp16 hi/lo planes in MFMA-A fragment order.
// Fragment (mb,kb): lane l holds A[mb*16 + (l&15)][kb*32 + (l>>4)*8 + 0..7].
// Coalesced global reads via LDS transpose. Block: 16 rows x 96 k.
// ---------------------------------------------------------------------------
__global__ __launch_bounds__(256) void k_prep_a(
    const float* __restrict__ x,
    const float* __restrict__ g0, const float* __restrict__ b0,
    const float* __restrict__ m0, const float* __restrict__ v0,
    f16* __restrict__ Ah, f16* __restrict__ Al)
{
    __shared__ float xl[16][97];
    const int tid = threadIdx.x;
    const int mb  = blockIdx.x / 7;
    const int kc  = blockIdx.x % 7;

    // load 16x96 floats = 384 float4, coalesced within rows
    #pragma unroll
    for (int i = 0; i < 2; ++i) {
        const int f4 = tid + 256 * i;
        if (f4 < 384) {
            const int row = f4 / 24;
            const int c4  = (f4 % 24) * 4;
            float4 v = *(const float4*)(x + (size_t)(mb * 16 + row) * FIN + kc * 96 + c4);
            xl[row][c4 + 0] = v.x; xl[row][c4 + 1] = v.y;
            xl[row][c4 + 2] = v.z; xl[row][c4 + 3] = v.w;
        }
    }
    __syncthreads();

    if (tid < 192) {
        const int fi   = tid >> 6;          // 0..2 kb-in-chunk
        const int lane = tid & 63;
        const int row  = lane & 15;
        const int koff = fi * 32 + ((lane >> 4) << 3);
        const float a0  = g0[row] / sqrtf(v0[row] + EPSBN);
        const float be0 = b0[row] - m0[row] * a0;
        half8 hi, lo;
        #pragma unroll
        for (int j = 0; j < 8; ++j) {
            const float xn = fmaf(a0, xl[row][koff + j], be0);
            const f16 h = (f16)xn;
            hi[j] = h;
            lo[j] = (f16)(xn - (float)h);
        }
        const int kb = kc * 3 + fi;
        const size_t idx = ((size_t)(mb * NKB + kb) * 64 + lane);
        *(half8*)(Ah + idx * 8) = hi;
        *(half8*)(Al + idx * 8) = lo;
    }
}

// ---------------------------------------------------------------------------
// Prep W: w1 -> fp16 hi/lo planes in MFMA-B fragment order.
// Fragment (nb,kb): lane l holds W[kb*32 + (l>>4)*8 + 0..7][nb*16 + (l&15)].
// Coalesced global reads via LDS transpose. Block: 32 k x 64 cols (4 nb).
// ---------------------------------------------------------------------------
__global__ __launch_bounds__(256) void k_prep_w(
    const float* __restrict__ w1, f16* __restrict__ Wh, f16* __restrict__ Wl)
{
    __shared__ float wl[32][65];
    const int tid = threadIdx.x;
    const int ng  = blockIdx.x;   // 0..31 (group of 4 nb)
    const int kb  = blockIdx.y;   // 0..20

    #pragma unroll
    for (int i = 0; i < 2; ++i) {
        const int f4  = tid + 256 * i;        // 0..511
        const int row = f4 >> 4;
        const int c4  = (f4 & 15) * 4;
        float4 v = *(const float4*)(w1 + (size_t)(kb * 32 + row) * HH + ng * 64 + c4);
        wl[row][c4 + 0] = v.x; wl[row][c4 + 1] = v.y;
        wl[row][c4 + 2] = v.z; wl[row][c4 + 3] = v.w;
    }
    __syncthreads();

    const int fi   = tid >> 6;     // 0..3
    const int lane = tid & 63;
    const int col  = fi * 16 + (lane & 15);
    const int kr   = (lane >> 4) << 3;
    half8 hi, lo;
    #pragma unroll
    for (int j = 0; j < 8; ++j) {
        const float wv = wl[kr + j][col];
        const f16 h = (f16)wv;
        hi[j] = h;
        lo[j] = (f16)(wv - (float)h);
    }
    const int nb = ng * 4 + fi;
    const size_t idx = ((size_t)(nb * NKB + kb) * 64 + lane);
    *(half8*)(Wh + idx * 8) = hi;
    *(half8*)(Wl + idx * 8) = lo;
}

// ---------------------------------------------------------------------------
// GEMM1 via MFMA fp16-split (hh + hl + lh), fused bias1/BN1/LIF epilogue.
// 64-thread blocks (1 wave), wave tile 32x32 (2x2 frags), grid 2048
// -> 8 blocks/CU = 2 waves/SIMD for TLP latency hiding. No LDS staging.
// ---------------------------------------------------------------------------
__global__ __launch_bounds__(64) void k_gemm1_mfma(
    const f16* __restrict__ Ah, const f16* __restrict__ Al,
    const f16* __restrict__ Wh, const f16* __restrict__ Wl,
    const float* __restrict__ bias1,
    const float* __restrict__ g1, const float* __restrict__ b1,
    const float* __restrict__ m1, const float* __restrict__ v1,
    float* __restrict__ S)
{
    __shared__ float lut[18];
    const int lane = threadIdx.x;
    if (lane < 18) lut[lane] = LIF_LUT[lane];

    const int bm  = blockIdx.x & 31;    // 32 m-tiles of 32 rows
    const int bn  = blockIdx.x >> 5;    // 64 n-tiles of 32 cols
    const int mb0 = bm * 2;
    const int nb0 = bn * 2;

    size_t baseA[2], baseB[2];
    #pragma unroll
    for (int m = 0; m < 2; ++m) baseA[m] = (size_t)(mb0 + m) * NKB * 64 + lane;
    #pragma unroll
    for (int n = 0; n < 2; ++n) baseB[n] = (size_t)(nb0 + n) * NKB * 64 + lane;

    const half8* pAh = (const half8*)Ah;
    const half8* pAl = (const half8*)Al;
    const half8* pWh = (const half8*)Wh;
    const half8* pWl = (const half8*)Wl;

    floatx4 acc[2][2];
    #pragma unroll
    for (int m = 0; m < 2; ++m)
        #pragma unroll
        for (int n = 0; n < 2; ++n) acc[m][n] = (floatx4){0.f,0.f,0.f,0.f};

    half8 a0h[2], a0l[2], b0h[2], b0l[2];
    half8 a1h[2], a1l[2], b1h[2], b1l[2];

#define LOADK(kb, ah, al, bh, bl) do {                                        \
    _Pragma("unroll") for (int m_ = 0; m_ < 2; ++m_) {                        \
        ah[m_] = pAh[baseA[m_] + (size_t)(kb) * 64];                          \
        al[m_] = pAl[baseA[m_] + (size_t)(kb) * 64]; }                        \
    _Pragma("unroll") for (int n_ = 0; n_ < 2; ++n_) {                        \
        bh[n_] = pWh[baseB[n_] + (size_t)(kb) * 64];                          \
        bl[n_] = pWl[baseB[n_] + (size_t)(kb) * 64]; }                        \
} while (0)

#define COMPUTE(ah, al, bh, bl) do {                                          \
    _Pragma("unroll") for (int m_ = 0; m_ < 2; ++m_)                          \
    _Pragma("unroll") for (int n_ = 0; n_ < 2; ++n_)                          \
        acc[m_][n_] = __builtin_amdgcn_mfma_f32_16x16x32_f16(                 \
            ah[m_], bh[n_], acc[m_][n_], 0, 0, 0);                            \
    _Pragma("unroll") for (int m_ = 0; m_ < 2; ++m_)                          \
    _Pragma("unroll") for (int n_ = 0; n_ < 2; ++n_)                          \
        acc[m_][n_] = __builtin_amdgcn_mfma_f32_16x16x32_f16(                 \
            ah[m_], bl[n_], acc[m_][n_], 0, 0, 0);                            \
    _Pragma("unroll") for (int m_ = 0; m_ < 2; ++m_)                          \
    _Pragma("unroll") for (int n_ = 0; n_ < 2; ++n_)                          \
        acc[m_][n_] = __builtin_amdgcn_mfma_f32_16x16x32_f16(                 \
            al[m_], bh[n_], acc[m_][n_], 0, 0, 0);                            \
} while (0)

    LOADK(0, a0h, a0l, b0h, b0l);
    for (int kb = 0; kb + 2 <= NKB; kb += 2) {
        LOADK(kb + 1, a1h, a1l, b1h, b1l);
        COMPUTE(a0h, a0l, b0h, b0l);
        if (kb + 2 < NKB) LOADK(kb + 2, a0h, a0l, b0h, b0l);
        COMPUTE(a1h, a1l, b1h, b1l);
    }
    COMPUTE(a0h, a0l, b0h, b0l);   // kb = 20 (NKB odd)
#undef LOADK
#undef COMPUTE

    __syncthreads();   // lut visible

    const float H16 = (float)(65536.0 / 65535.0);
    const int   r4  = (lane >> 4) << 2;

    float a1c[4], be1c[4];
    #pragma unroll
    for (int j = 0; j < 4; ++j) {
        const int p = r4 + j;
        a1c[j]  = g1[p] / sqrtf(v1[p] + EPSBN);
        be1c[j] = b1[p] - m1[p] * a1c[j];
    }

    #pragma unroll
    for (int n = 0; n < 2; ++n) {
        const int col = (nb0 + n) * 16 + (lane & 15);
        const float bs = bias1[col];
        #pragma unroll
        for (int m = 0; m < 2; ++m) {
            const int rowbase = (mb0 + m) * 16 + r4;
            #pragma unroll
            for (int j = 0; j < 4; ++j) {
                const float h = fmaf(a1c[j], acc[m][n][j] + bs, be1c[j]);
                float s = 0.f;
                if (h >= H16) {
                    const float r = 1.f - __builtin_amdgcn_rcpf(h);
                    int mi = (int)ceilf(-__log2f(r));
                    mi = mi < 1 ? 1 : (mi > 17 ? 17 : mi);
                    s = lut[mi];
                }
                S[(size_t)(rowbase + j) * HH + col] = s;
            }
        }
    }
}

// ---------------------------------------------------------------------------
// Fallback fp32 GEMM1 (round-2 kernel) used if ws_size is too small.
// ---------------------------------------------------------------------------
__global__ __launch_bounds__(256) void k_gemm1_fp32(
    const float* __restrict__ x, const float* __restrict__ w1,
    const float* __restrict__ bias1,
    const float* __restrict__ g0, const float* __restrict__ b0,
    const float* __restrict__ m0, const float* __restrict__ v0,
    const float* __restrict__ g1, const float* __restrict__ b1,
    const float* __restrict__ m1, const float* __restrict__ v1,
    float* __restrict__ S)
{
    __shared__ float As[16][36];
    __shared__ float Bs[16][68];

    const int tid = threadIdx.x;
    const int bx  = blockIdx.x;
    const int by  = blockIdx.y;

    const int ar   = tid & 31;
    const int ak   = (tid >> 5) << 1;
    const int grow = by * 32 + ar;
    const int pA   = grow & 15;
    const float a0  = g0[pA] / sqrtf(v0[pA] + EPSBN);
    const float be0 = b0[pA] - m0[pA] * a0;
    const float* xrow = x + (size_t)grow * FIN;

    const int brk = tid >> 4;
    const int bcc = (tid & 15) << 2;
    const float* wp = w1 + (size_t)brk * HH + bx * 64 + bcc;

    const int tx = tid & 15;
    const int ty = tid >> 4;

    float acc[2][4];
    #pragma unroll
    for (int i = 0; i < 2; ++i)
        #pragma unroll
        for (int j = 0; j < 4; ++j) acc[i][j] = 0.f;

    float2 aPre = *(const float2*)(xrow + ak);
    float4 bPre = *(const float4*)(wp);

    for (int kt = 0; kt < FIN; kt += 16) {
        As[ak + 0][ar] = fmaf(a0, aPre.x, be0);
        As[ak + 1][ar] = fmaf(a0, aPre.y, be0);
        *(float4*)&Bs[brk][bcc] = bPre;
        __syncthreads();
        if (kt + 16 < FIN) {
            aPre = *(const float2*)(xrow + kt + 16 + ak);
            bPre = *(const float4*)(wp + (size_t)(kt + 16) * HH);
        }
        #pragma unroll
        for (int k = 0; k < 16; ++k) {
            float2 a2 = *(const float2*)&As[k][ty << 1];
            float4 b4 = *(const float4*)&Bs[k][tx << 2];
            float aa[2] = {a2.x, a2.y};
            float bb[4] = {b4.x, b4.y, b4.z, b4.w};
            #pragma unroll
            for (int i = 0; i < 2; ++i)
                #pragma unroll
                for (int j = 0; j < 4; ++j)
                    acc[i][j] = fmaf(aa[i], bb[j], acc[i][j]);
        }
        __syncthreads();
    }

    const float KC[16] = {
        (1.0f-0x1p-16f)*0.0625f,(1.0f-0x1p-15f)*0.0625f,(1.0f-0x1p-14f)*0.0625f,(1.0f-0x1p-13f)*0.0625f,
        (1.0f-0x1p-12f)*0.0625f,(1.0f-0x1p-11f)*0.0625f,(1.0f-0x1p-10f)*0.0625f,(1.0f-0x1p-9f)*0.0625f,
        (1.0f-0x1p-8f)*0.0625f,(1.0f-0x1p-7f)*0.0625f,(1.0f-0x1p-6f)*0.0625f,(1.0f-0x1p-5f)*0.0625f,
        (1.0f-0x1p-4f)*0.0625f,(1.0f-0x1p-3f)*0.0625f,(1.0f-0x1p-2f)*0.0625f,(1.0f-0x1p-1f)*0.0625f
    };

    const int col0 = bx * 64 + (tx << 2);
    float4 bias4 = *(const float4*)(bias1 + col0);
    const float bias_arr[4] = {bias4.x, bias4.y, bias4.z, bias4.w};

    #pragma unroll
    for (int i = 0; i < 2; ++i) {
        const int r = by * 32 + (ty << 1) + i;
        const int p = r & 15;
        const float a1  = g1[p] / sqrtf(v1[p] + EPSBN);
        const float be1 = b1[p] - m1[p] * a1;
        float out4[4];
        #pragma unroll
        for (int j = 0; j < 4; ++j) {
            const float h = fmaf(a1, acc[i][j] + bias_arr[j], be1);
            float v = 0.f, s = 0.f;
            #pragma unroll
            for (int t = 0; t < 16; ++t) {
                v = v + (h - v) * 0.5f;
                if (v >= 1.0f) { s += KC[t]; v = 0.f; }
            }
            out4[j] = s;
        }
        float4 sv; sv.x = out4[0]; sv.y = out4[1]; sv.z = out4[2]; sv.w = out4[3];
        *(float4*)(S + (size_t)r * HH + col0) = sv;
    }
}

// ---------------------------------------------------------------------------
// Kernel 2a: partial GEMM2; Kernel 2b: reduce + BN2/bias2/ns-LIF-mean + tanh.
// ---------------------------------------------------------------------------
__global__ __launch_bounds__(256) void k_gemm2_part(
    const float* __restrict__ S, const float* __restrict__ w2,
    float* __restrict__ part)
{
    __shared__ float w2s[8192];
    const int tid = threadIdx.x;
    const int rg  = blockIdx.x;
    const int kc  = blockIdx.y;

    const float4* src = (const float4*)(w2 + (size_t)kc * 8192);
    #pragma unroll
    for (int i = tid; i < 2048; i += 256) ((float4*)w2s)[i] = src[i];
    __syncthreads();

    const int rw  = tid >> 5;
    const int col = tid & 31;
    const int row = rg * 8 + rw;
    const float* Sp = S + (size_t)row * HH + kc * 256;

    float acc0 = 0.f, acc1 = 0.f;
    #pragma unroll 4
    for (int j = 0; j < 256; j += 4) {
        float4 s4 = *(const float4*)(Sp + j);
        acc0 = fmaf(s4.x, w2s[(j + 0) * 32 + col], acc0);
        acc1 = fmaf(s4.y, w2s[(j + 1) * 32 + col], acc1);
        acc0 = fmaf(s4.z, w2s[(j + 2) * 32 + col], acc0);
        acc1 = fmaf(s4.w, w2s[(j + 3) * 32 + col], acc1);
    }
    part[((size_t)kc * MM + row) * AA + col] = acc0 + acc1;
}

__global__ __launch_bounds__(256) void k_finish(
    const float* __restrict__ part, const float* __restrict__ bias2,
    const float* __restrict__ g2, const float* __restrict__ b2,
    const float* __restrict__ m2, const float* __restrict__ v2,
    float* __restrict__ out)
{
    const int i   = blockIdx.x * 256 + threadIdx.x;
    const int col = i & 31;
    const int row = i >> 5;
    const int p   = row & 15;
    float acc = 0.f;
    #pragma unroll
    for (int s = 0; s < 8; ++s) acc += part[(size_t)s * MM * AA + i];
    const float a2   = g2[p] / sqrtf(v2[p] + EPSBN);
    const float be2  = b2[p] - m2[p] * a2;
    const float Csum = 0.9375f + 0x1p-20f;
    const float val  = fmaf(a2, acc + Csum * bias2[col], Csum * be2);
    out[i] = 2.0f * tanhf(val);
}

extern "C" void kernel_launch(void* const* d_in, const int* in_sizes, int n_in,
                              void* d_out, int out_size, void* d_ws, size_t ws_size,
                              hipStream_t stream) {
    (void)in_sizes; (void)n_in; (void)out_size;
    const float* x     = (const float*)d_in[0];
    const float* w1    = (const float*)d_in[1];
    const float* bias1 = (const float*)d_in[2];
    const float* w2    = (const float*)d_in[3];
    const float* bias2 = (const float*)d_in[4];
    const float* g0 = (const float*)d_in[5];
    const float* b0 = (const float*)d_in[6];
    const float* m0 = (const float*)d_in[7];
    const float* v0 = (const float*)d_in[8];
    const float* g1 = (const float*)d_in[9];
    const float* b1 = (const float*)d_in[10];
    const float* m1 = (const float*)d_in[11];
    const float* v1 = (const float*)d_in[12];
    const float* g2 = (const float*)d_in[13];
    const float* b2 = (const float*)d_in[14];
    const float* m2 = (const float*)d_in[15];
    const float* v2 = (const float*)d_in[16];
    float* out = (float*)d_out;

    // ws layout (MFMA path): Ah 1.3M | Al 1.3M | Wh 2.6M | Wl 2.6M | S 8M | part 1M
    const size_t offAl   = 1376256;
    const size_t offWh   = 2752512;
    const size_t offWl   = 5505024;
    const size_t offS    = 8257536;
    const size_t offPart = offS + 8388608;
    const size_t needed  = offPart + 1048576;   // 17694720

    if (ws_size >= needed) {
        f16* Ah = (f16*)d_ws;
        f16* Al = (f16*)((char*)d_ws + offAl);
        f16* Wh = (f16*)((char*)d_ws + offWh);
        f16* Wl = (f16*)((char*)d_ws + offWl);
        float* S    = (float*)((char*)d_ws + offS);
        float* part = (float*)((char*)d_ws + offPart);

        k_prep_a<<<448, 256, 0, stream>>>(x, g0, b0, m0, v0, Ah, Al);
        k_prep_w<<<dim3(32, 21), 256, 0, stream>>>(w1, Wh, Wl);
        k_gemm1_mfma<<<2048, 64, 0, stream>>>(Ah, Al, Wh, Wl, bias1,
                                              g1, b1, m1, v1, S);
        k_gemm2_part<<<dim3(128, 8), 256, 0, stream>>>(S, w2, part);
        k_finish<<<dim3(128), 256, 0, stream>>>(part, bias2, g2, b2, m2, v2, out);
    } else {
        float* S    = (float*)d_ws;
        float* part = (float*)((char*)d_ws + (size_t)MM * HH * sizeof(float));
        k_gemm1_fp32<<<dim3(32, 32), 256, 0, stream>>>(x, w1, bias1,
                                                       g0, b0, m0, v0,
                                                       g1, b1, m1, v1, S);
        k_gemm2_part<<<dim3(128, 8), 256, 0, stream>>>(S, w2, part);
        k_finish<<<dim3(128), 256, 0, stream>>>(part, bias2, g2, b2, m2, v2, out);
    }
}